// Round 8
// baseline (226.561 us; speedup 1.0000x reference)
//
#include <hip/hip_runtime.h>
#include <math.h>

// Problem constants
#define BB 2
#define TT 1024
#define CC 1024
#define HH 16
#define HD 64
#define SS 512
#define LL 1024
#define ST 1536   // S+T
#define MM 2560   // L+S+T
#define C3 3072   // 3*C

typedef __attribute__((ext_vector_type(8))) short short8;    // 8 bf16 (4 VGPRs)
typedef __attribute__((ext_vector_type(4))) short short4v;
typedef __attribute__((ext_vector_type(4))) float floatx4;

__device__ __forceinline__ unsigned short f2bf(float f) {
    union { float f; unsigned u; } v; v.f = f;
    unsigned r = v.u + 0x7fffu + ((v.u >> 16) & 1u);   // RNE
    return (unsigned short)(r >> 16);
}
__device__ __forceinline__ float bf2f(short s) {
    union { unsigned u; float f; } v;
    v.u = ((unsigned)(unsigned short)s) << 16;
    return v.f;
}

// async global->LDS, 16B per lane; LDS side is wave-uniform base + lane*16
__device__ __forceinline__ void gl_lds16(const short* g, short* l) {
    __builtin_amdgcn_global_load_lds(
        (const __attribute__((address_space(1))) void*)g,
        (__attribute__((address_space(3))) void*)l,
        16, 0, 0);
}

// ---------------------------------------------------------------------------
// prep_all: all independent prep work in ONE launch, partitioned by blockIdx.
//   [0,3072)    cast_xcat   xcat fp32 -> Xb bf16
//   [3072,6144) wtrans(w_attn)  [1024][3072] -> WaT [3072][1024] bf16
//   [6144,7168) wtrans(w_proj)  [1024][1024] -> WpT [1024][1024] bf16
//   [7168,7360) rope_table
//   [7360,7872) long_k -> Kb rows [0,L), long_v -> Vtr [bh][d][j] transposed
// ---------------------------------------------------------------------------
__global__ __launch_bounds__(256)
void prep_all(const float* __restrict__ x, const float* __restrict__ stm,
              const float* __restrict__ w_attn, const float* __restrict__ w_proj,
              const float* __restrict__ lk, const float* __restrict__ lv,
              short* __restrict__ Xb, short* __restrict__ WaT,
              short* __restrict__ WpT, short* __restrict__ Kg,
              short* __restrict__ Vt, float* __restrict__ tab)
{
    __shared__ __align__(16) char smem[9216];
    const int blk = blockIdx.x;
    const int t = threadIdx.x;

    if (blk < 3072) {
        // ---- cast_xcat ----
        const int idx = blk * 256 + t;
        const int rg  = idx >> 8;
        const int c   = (idx & 255) << 2;
        const int b   = rg >= ST;
        const int r   = rg - b * ST;
        const float* src = (r < SS) ? (stm + ((size_t)b * SS + r) * CC + c)
                                    : (x   + ((size_t)b * TT + (r - SS)) * CC + c);
        float4 v = *(const float4*)src;
        short4v o;
        o.x = (short)f2bf(v.x); o.y = (short)f2bf(v.y);
        o.z = (short)f2bf(v.z); o.w = (short)f2bf(v.w);
        *(short4v*)(Xb + (size_t)rg * CC + c) = o;
    } else if (blk < 7168) {
        // ---- weight transpose+cast ----
        const bool isA = blk < 6144;
        const int bx = isA ? (blk - 3072) : (blk - 6144);
        const int nblk = isA ? 96 : 32;
        const int Nd = isA ? C3 : CC;
        const float* W = isA ? w_attn : w_proj;
        short* WT = isA ? WaT : WpT;
        const int n0 = (bx % nblk) * 32, k0 = (bx / nblk) * 32;
        float (*Tl)[33] = (float(*)[33])smem;
        const int r = t >> 3, c4 = (t & 7) << 2;
        float4 v = *(const float4*)(W + (size_t)(k0 + r) * Nd + n0 + c4);
        Tl[r][c4 + 0] = v.x; Tl[r][c4 + 1] = v.y;
        Tl[r][c4 + 2] = v.z; Tl[r][c4 + 3] = v.w;
        __syncthreads();
        short4v o;
        o.x = (short)f2bf(Tl[c4 + 0][r]); o.y = (short)f2bf(Tl[c4 + 1][r]);
        o.z = (short)f2bf(Tl[c4 + 2][r]); o.w = (short)f2bf(Tl[c4 + 3][r]);
        *(short4v*)(WT + (size_t)(n0 + r) * CC + k0 + c4) = o;
    } else if (blk < 7360) {
        // ---- rope table ----
        const int idx = (blk - 7168) * 256 + t;   // < 49152
        const int r = idx >> 5, e = idx & 31;
        const float inv = powf(10000.0f, -(float)e * (1.0f / 32.0f));
        float sn, cs;
        sincosf((float)r * inv, &sn, &cs);
        tab[idx * 2] = cs;
        tab[idx * 2 + 1] = sn;
    } else {
        // ---- long_k -> Kb (cast), long_v -> Vtr (cast + transpose) ----
        const int bx = blk - 7360;                 // < 512
        const int bh = bx >> 4, j0 = (bx & 15) * 64;
        const int b = bh >> 4, h = bh & 15;
        short (*Tl)[72] = (short(*)[72])smem;
        const int jr = t >> 2, c16 = (t & 3) << 4;
        const size_t si = (((size_t)b * LL + j0 + jr) * HH + h) * HD + c16;
        short kk[16], vv[16];
        #pragma unroll
        for (int u = 0; u < 4; u++) {
            float4 kv = *(const float4*)(lk + si + 4 * u);
            float4 vf = *(const float4*)(lv + si + 4 * u);
            kk[4*u+0] = (short)f2bf(kv.x); kk[4*u+1] = (short)f2bf(kv.y);
            kk[4*u+2] = (short)f2bf(kv.z); kk[4*u+3] = (short)f2bf(kv.w);
            vv[4*u+0] = (short)f2bf(vf.x); vv[4*u+1] = (short)f2bf(vf.y);
            vv[4*u+2] = (short)f2bf(vf.z); vv[4*u+3] = (short)f2bf(vf.w);
        }
        short* kdst = Kg + ((size_t)bh * MM + j0 + jr) * HD + c16;
        *(short8*)kdst       = *(short8*)&kk[0];
        *(short8*)(kdst + 8) = *(short8*)&kk[8];
        #pragma unroll
        for (int u = 0; u < 16; u++) Tl[jr][c16 + u] = vv[u];
        __syncthreads();
        const int r = t >> 2, c = t & 3;    // r = d index, c = j chunk
        short o0[8], o1[8];
        #pragma unroll
        for (int u = 0; u < 8; u++) {
            o0[u] = Tl[c * 16 + u][r];
            o1[u] = Tl[c * 16 + 8 + u][r];
        }
        short* vdst = Vt + ((size_t)bh * HD + r) * MM + j0 + c * 16;
        *(short8*)vdst       = *(short8*)&o0[0];
        *(short8*)(vdst + 8) = *(short8*)&o1[0];
    }
}

// ---------------------------------------------------------------------------
// Kernel: qkv MFMA GEMM — r6 structure (128x64 tiles, LDS union, 4 blk/CU).
//   Measured r7: ~28.6 us = ~675 TF — near structural ceiling for this size.
// ---------------------------------------------------------------------------
__global__ __launch_bounds__(256)
void qkv_gemm(const short* __restrict__ A, const short* __restrict__ Bt,
              const float* __restrict__ RT,
              short* __restrict__ Qo, short* __restrict__ Ko, short* __restrict__ Vo)
{
    __shared__ __align__(16) short U[12288];   // 24 KB
    short* As = U;            // [128][64] shorts  (K-loop)
    short* Bs = U + 8192;     // [64][64]  shorts  (K-loop)
    short* Et = U;            // epilogue overlay: [128][68] (Q/K) or [64][132] (V)

    const int b = blockIdx.z;
    const int row0 = blockIdx.y * 128, col0 = blockIdx.x * 64;
    const int tid = threadIdx.x;
    const int w = tid >> 6, l = tid & 63, quad = l >> 4, cl = l & 15;
    const int wr = w >> 1, wc = w & 1;   // wave tile: rows wr*64..+64, cols wc*32..+32

    const int reg  = col0 >> 10;
    const bool hasQ = (row0 >= SS);
    if (reg == 0 && !hasQ) return;

    // staging lane assignment (r4-verified pattern)
    const int srow8 = l >> 3;            // 0..7: row within 8-row issue group
    const int sl8   = l & 7;             // 16B slot within the 64-short row
    const int ch0   = (sl8 - (srow8 >> 1)) & 7;
    const int ch1   = (sl8 - 4 - (srow8 >> 1)) & 7;
    // A: wave w stages rows [w*32, w*32+32), 4 issues of 8 rows
    const short* gA = A + ((size_t)b * ST + row0 + w * 32 + srow8) * CC;
    short* lA = &As[(w * 32) * 64 + l * 8];
    // B: wave w stages rows [w*16, w*16+16), 2 issues of 8 rows
    const short* gB = Bt + ((size_t)(col0 + w * 16 + srow8)) * CC;
    short* lB = &Bs[(w * 16) * 64 + l * 8];

    floatx4 acc[4][2];
    #pragma unroll
    for (int mi = 0; mi < 4; mi++)
        #pragma unroll
        for (int ni = 0; ni < 2; ni++) acc[mi][ni] = (floatx4){0.f, 0.f, 0.f, 0.f};

    for (int k0 = 0; k0 < CC; k0 += 64) {
        __syncthreads();
        gl_lds16(gA + k0 + ch0 * 8,                     lA);
        gl_lds16(gA + (size_t)8  * CC + k0 + ch1 * 8,   lA + 512);
        gl_lds16(gA + (size_t)16 * CC + k0 + ch0 * 8,   lA + 1024);
        gl_lds16(gA + (size_t)24 * CC + k0 + ch1 * 8,   lA + 1536);
        gl_lds16(gB + k0 + ch0 * 8,                     lB);
        gl_lds16(gB + (size_t)8  * CC + k0 + ch1 * 8,   lB + 512);
        __syncthreads();
        #pragma unroll
        for (int ks = 0; ks < 2; ks++) {
            const int slot = (ks * 4 + quad + (cl >> 1)) & 7;
            short8 af[4], bf[2];
            #pragma unroll
            for (int mi = 0; mi < 4; mi++)
                af[mi] = *(const short8*)&As[(wr * 64 + mi * 16 + cl) * 64 + slot * 8];
            #pragma unroll
            for (int ni = 0; ni < 2; ni++)
                bf[ni] = *(const short8*)&Bs[(wc * 32 + ni * 16 + cl) * 64 + slot * 8];
            #pragma unroll
            for (int mi = 0; mi < 4; mi++)
                #pragma unroll
                for (int ni = 0; ni < 2; ni++)
                    acc[mi][ni] = __builtin_amdgcn_mfma_f32_16x16x32_bf16(
                        af[mi], bf[ni], acc[mi][ni], 0, 0, 0);
        }
    }

    __syncthreads();   // As/Bs dead -> Et overlay becomes safe

    const int hh = (col0 & 1023) >> 6;   // single head per 64-col tile

    #pragma unroll
    for (int ni = 0; ni < 2; ni++) {
        const int c_local = wc * 32 + ni * 16 + cl;   // [0,64) = d within head
        const int e = c_local >> 1;
        #pragma unroll
        for (int mi = 0; mi < 4; mi++) {
            #pragma unroll
            for (int r = 0; r < 4; r++) {
                const int R_local = wr * 64 + mi * 16 + quad * 4 + r;
                const int R = row0 + R_local;
                float v = acc[mi][ni][r];
                if (reg < 2) {
                    const float2 tt = ((const float2*)RT)[R * 32 + e];
                    union { float f; int i; } vu; vu.f = v;
                    const float po = __int_as_float(
                        __builtin_amdgcn_mov_dpp(vu.i, 0xB1, 0xf, 0xf, true));
                    float out = ((cl & 1) == 0) ? (v * tt.x - po * tt.y)
                                                : (po * tt.y + v * tt.x);
                    union { float f; int i; } ou; ou.f = out;
                    const int oo = __builtin_amdgcn_mov_dpp(ou.i, 0xB1, 0xf, 0xf, true);
                    if ((cl & 1) == 0) {
                        unsigned word;
                        asm("v_cvt_pk_bf16_f32 %0, %1, %2"
                            : "=v"(word) : "v"(out), "v"(__int_as_float(oo)));
                        *(unsigned*)&Et[R_local * 68 + c_local] = word;
                    }
                } else {
                    Et[c_local * 132 + R_local] = (short)f2bf(v);
                }
            }
        }
    }
    __syncthreads();

    if (reg < 2) {
        short* dstb = (reg == 0)
            ? Qo + (((size_t)b * HH + hh) * TT + (row0 - SS)) * HD
            : Ko + (((size_t)b * HH + hh) * MM + LL + row0) * HD;
        #pragma unroll
        for (int it = 0; it < 4; it++) {
            const int idx = it * 2048 + tid * 8;   // r*64 + d, r<128
            const int r = idx >> 6, d = idx & 63;
            short4v v0 = *(const short4v*)&Et[r * 68 + d];
            short4v v1 = *(const short4v*)&Et[r * 68 + d + 4];
            short8 vv;
            #pragma unroll
            for (int u = 0; u < 4; u++) { vv[u] = v0[u]; vv[u + 4] = v1[u]; }
            *(short8*)(dstb + idx) = vv;
        }
    } else {
        #pragma unroll
        for (int it = 0; it < 4; it++) {
            const int idx = it * 2048 + tid * 8;   // d*128 + r0, d<64
            const int d = idx >> 7, r0 = idx & 127;
            short4v v0 = *(const short4v*)&Et[d * 132 + r0];
            short4v v1 = *(const short4v*)&Et[d * 132 + r0 + 4];
            short8 vv;
            #pragma unroll
            for (int u = 0; u < 4; u++) { vv[u] = v0[u]; vv[u + 4] = v1[u]; }
            *(short8*)(Vo + (((size_t)b * HH + hh) * HD + d) * MM + LL + row0 + r0) = vv;
        }
    }
}

// ---------------------------------------------------------------------------
// Kernel: MFMA flash attention v3.1 + T5 setprio (r7: 46.1 us, kept).
// ---------------------------------------------------------------------------
#define PSP 72
#define PSW (32 * PSP)
#define VS_OFF 4096
#define PS_OFF 8192
__global__ __launch_bounds__(256, 4)
void attn_mfma(const short* __restrict__ Qg, const short* __restrict__ Kg,
               const short* __restrict__ Vt, short* __restrict__ Op,
               float* __restrict__ Lp)
{
    // L layout (shorts): [0,4096) Ks [key][d] | [4096,8192) Vs [d][key]
    //                    [8192,17408) Ps 4 waves x [32 q][72]
    // Ys (post-loop) = L[0 .. 128*68) overlapping Ks/Vs/Ps-head explicitly.
    __shared__ __align__(16) short L[17408];

    const int bh = blockIdx.x;
    const int q0 = (7 - blockIdx.y) * 128;   // heavy blocks dispatch first
    const int piece = blockIdx.z;            // 0..3 split-K
    const int tid = threadIdx.x, w = tid >> 6, l = tid & 63;
    const int quad = l >> 4, cl = l & 15;

    // Q fragments: two 16-q groups per wave
    short8 qa[2][2];
    #pragma unroll
    for (int g = 0; g < 2; g++) {
        const short* qptr = Qg + ((size_t)bh * TT + q0 + w * 32 + g * 16 + cl) * HD + quad * 8;
        qa[g][0] = *(const short8*)qptr;
        qa[g][1] = *(const short8*)(qptr + 32);
    }

    floatx4 o[2][4];
    float rs[2][4];
    #pragma unroll
    for (int g = 0; g < 2; g++)
        #pragma unroll
        for (int r = 0; r < 4; r++) {
            rs[g][r] = 0.f;
            o[g][r] = (floatx4){0.f, 0.f, 0.f, 0.f};
        }

    // async staging lane assignment (verified r5/r6)
    const int srow_lo = l >> 3;
    const int sslot  = l & 7;
    const int ch0 = (sslot - (srow_lo >> 1)) & 7;
    const int ch1 = (sslot - (4 + (srow_lo >> 1))) & 7;
    const int rowi0 = w * 16 + srow_lo;
    const int rowi1 = w * 16 + 8 + srow_lo;
    const short* kgb = Kg + (size_t)bh * MM * HD;
    const short* vbase = Vt + (size_t)bh * HD * MM;
    short* ldsK0 = &L[(w * 16) * 64];
    short* ldsK1 = &L[(w * 16 + 8) * 64];
    short* ldsV0 = &L[VS_OFF + (w * 16) * 64];
    short* ldsV1 = &L[VS_OFF + (w * 16 + 8) * 64];

    const int fsA = (quad + (cl >> 1)) & 7;
    const int fsB = (quad + 4 + (cl >> 1)) & 7;
    const int psA = (quad + 2 * cl) & 7;       // P dewizzle: slot=(chunk+2*row)&7
    const int psB = (quad + 4 + 2 * cl) & 7;

    const int ntiles = (LL + SS + q0) / 64 + 2;
    const int t_begin = piece * ntiles / 4;
    const int t_end   = (piece + 1) * ntiles / 4;

    for (int t = t_begin; t < t_end; t++) {
        const int j0 = t * 64;
        __syncthreads();
        gl_lds16(kgb + (size_t)(j0 + rowi0) * HD + ch0 * 8, ldsK0);
        gl_lds16(kgb + (size_t)(j0 + rowi1) * HD + ch1 * 8, ldsK1);
        gl_lds16(vbase + (size_t)rowi0 * MM + j0 + ch0 * 8, ldsV0);
        gl_lds16(vbase + (size_t)rowi1 * MM + j0 + ch1 * 8, ldsV1);
        __syncthreads();

        // ---- S = Q.K^T for both q-groups (shared K frag reads) ----
        __builtin_amdgcn_s_setprio(1);
        floatx4 s[2][4];
        #pragma unroll
        for (int ks = 0; ks < 4; ks++) {
            const int krow = ks * 16 + cl;
            short8 kf0 = *(const short8*)&L[krow * 64 + fsA * 8];
            short8 kf1 = *(const short8*)&L[krow * 64 + fsB * 8];
            #pragma unroll
            for (int g = 0; g < 2; g++) {
                floatx4 z = (floatx4){0.f, 0.f, 0.f, 0.f};
                z = __builtin_amdgcn_mfma_f32_16x16x32_bf16(qa[g][0], kf0, z, 0, 0, 0);
                z = __builtin_amdgcn_mfma_f32_16x16x32_bf16(qa[g][1], kf1, z, 0, 0, 0);
                s[g][ks] = z;
            }
        }
        __builtin_amdgcn_s_setprio(0);

        // ---- no-max softmax: p = exp(s/8); per-lane partial sums ----
        const bool tailzone = (t >= ntiles - 2);
        #pragma unroll
        for (int g = 0; g < 2; g++) {
            const int qgb = LL + SS + q0 + w * 32 + g * 16;
            #pragma unroll
            for (int ks = 0; ks < 4; ks++) {
                #pragma unroll
                for (int r = 0; r < 4; r++) {
                    float sv = s[g][ks][r] * 0.125f;
                    if (tailzone && (j0 + ks * 16 + cl > qgb + quad * 4 + r))
                        sv = -INFINITY;
                    const float p = __expf(sv);
                    rs[g][r] += p;
                    const int qrw = quad * 4 + r;
                    const int slot = (ks * 2 + (cl >> 3) + 2 * qrw) & 7;
                    L[PS_OFF + w * PSW + (g * 16 + qrw) * PSP + slot * 8 + (cl & 7)] =
                        (short)f2bf(p);
                }
            }
        }

        // wave-private LDS write->read: drain ds queue, pin ordering
        __builtin_amdgcn_s_waitcnt(0xc07f);   // lgkmcnt(0)
        __builtin_amdgcn_wave_barrier();

        // ---- O += P.V (shared V frag reads) ----
        short8 pf[2][2];
        #pragma unroll
        for (int g = 0; g < 2; g++) {
            pf[g][0] = *(const short8*)&L[PS_OFF + w * PSW + (g * 16 + cl) * PSP + psA * 8];
            pf[g][1] = *(const short8*)&L[PS_OFF + w * PSW + (g * 16 + cl) * PSP + psB * 8];
        }
        __builtin_amdgcn_s_setprio(1);
        #pragma unroll
        for (int nt = 0; nt < 4; nt++) {
            const int drow = nt * 16 + cl;
            short8 vf0 = *(const short8*)&L[VS_OFF + drow * 64 + fsA * 8];
            short8 vf1 = *(const short8*)&L[VS_OFF + drow * 64 + fsB * 8];
            #pragma unroll
            for (int g = 0; g < 2; g++) {
                o[g][nt] = __builtin_amdgcn_mfma_f32_16x16x32_bf16(pf[g][0], vf0, o[g][nt], 0, 0, 0);
                o[g][nt] = __builtin_amdgcn_mfma_f32_16x16x32_bf16(pf[g][1], vf1, o[g][nt], 0, 0, 0);
            }
        }
        __builtin_amdgcn_s_setprio(0);
    }

    // ---- deferred l reduction (only shuffles in the kernel) ----
    #pragma unroll
    for (int g = 0; g < 2; g++)
        #pragma unroll
        for (int r = 0; r < 4; r++) {
            float t2 = rs[g][r];
            t2 += __shfl_xor(t2, 1);
            t2 += __shfl_xor(t2, 2);
            t2 += __shfl_xor(t2, 4);
            t2 += __shfl_xor(t2, 8);
            if (cl == 0)
                Lp[piece * 32768 + bh * 1024 + q0 + w * 32 + g * 16 + quad * 4 + r] = t2;
        }

    // ---- stage raw partial O -> coalesced store (Ys = L[0..8704), explicit) ----
    __syncthreads();   // all waves done reading Ks/Vs/Ps
    #pragma unroll
    for (int g = 0; g < 2; g++)
        #pragma unroll
        for (int r = 0; r < 4; r++) {
            const int ql = w * 32 + g * 16 + quad * 4 + r;
            #pragma unroll
            for (int nt = 0; nt < 4; nt++)
                L[ql * 68 + nt * 16 + cl] = (short)f2bf(o[g][nt][r]);
        }
    __syncthreads();
    short* ob = Op + ((size_t)(piece * 32 + bh) * 1024 + q0) * 64;
    #pragma unroll
    for (int it = 0; it < 4; it++) {
        const int idx = it * 2048 + tid * 8;   // q*64 + d, q<128
        const int q = idx >> 6, d = idx & 63;
        short4v v0 = *(const short4v*)&L[q * 68 + d];
        short4v v1 = *(const short4v*)&L[q * 68 + d + 4];
        short8 vv;
        #pragma unroll
        for (int u = 0; u < 4; u++) { vv[u] = v0[u]; vv[u + 4] = v1[u]; }
        *(short8*)(ob + idx) = vv;
    }
}

// ---------------------------------------------------------------------------
// Kernel: combine 4 split-K pieces (raw O sums + l sums) -> Yatt bf16
// ---------------------------------------------------------------------------
__global__ __launch_bounds__(256)
void attn_combine(const short* __restrict__ Op, const float* __restrict__ Lp,
                  short* __restrict__ Yatt)
{
    const int idx = blockIdx.x * 256 + threadIdx.x;   // < 262144
    const int row = idx >> 3;            // bh*1024 + q
    const int seg = (idx & 7) << 3;
    const float lsum = Lp[row] + Lp[32768 + row] + Lp[65536 + row] + Lp[98304 + row];
    const float inv = 1.0f / lsum;
    float acc[8] = {0.f, 0.f, 0.f, 0.f, 0.f, 0.f, 0.f, 0.f};
    #pragma unroll
    for (int p = 0; p < 4; p++) {
        short8 v = *(const short8*)(Op + ((size_t)(p * 32768) + row) * 64 + seg);
        #pragma unroll
        for (int u = 0; u < 8; u++) acc[u] += bf2f(v[u]);
    }
    short8 o8;
    #pragma unroll
    for (int u = 0; u < 8; u++) o8[u] = (short)f2bf(acc[u] * inv);
    const int bh = row >> 10, q = row & 1023;
    const int b = bh >> 4, h = bh & 15;
    *(short8*)(Yatt + ((size_t)b * TT + q) * CC + h * 64 + seg) = o8;
}

// ---------------------------------------------------------------------------
// Kernel: proj MFMA GEMM, 64x64 tiles (512 blocks -> 2/CU) — r4-proven
// version. 4 waves 2x2, each wave 32x32. Async staging.
// ---------------------------------------------------------------------------
__global__ __launch_bounds__(256)
void proj_gemm(const short* __restrict__ A, const short* __restrict__ Bt,
               float* __restrict__ Co)
{
    __shared__ short As[64 * 32];
    __shared__ short Bs[64 * 32];
    const int row0 = blockIdx.y * 64, col0 = blockIdx.x * 64;
    const int tid = threadIdx.x;
    const int w = tid >> 6, l = tid & 63, quad = l >> 4, cl = l & 15;
    const int wr = w >> 1, wc = w & 1;

    const int srow = tid >> 2;               // 0..63
    const int schunk = ((tid & 3) - ((srow & 15) >> 1)) & 3;
    const short* gA = A + (size_t)(row0 + srow) * CC + schunk * 8;
    const short* gB = Bt + (size_t)(col0 + srow) * CC + schunk * 8;
    short* lA = &As[tid * 8];
    short* lB = &Bs[tid * 8];

    const int fs = (quad + (cl >> 1)) & 3;

    floatx4 acc[2][2];
    #pragma unroll
    for (int mi = 0; mi < 2; mi++)
        #pragma unroll
        for (int ni = 0; ni < 2; ni++) acc[mi][ni] = (floatx4){0.f, 0.f, 0.f, 0.f};

    for (int k0 = 0; k0 < CC; k0 += 32) {
        __syncthreads();
        gl_lds16(gA + k0, lA);
        gl_lds16(gB + k0, lB);
        __syncthreads();
        short8 af[2], bf[2];
        #pragma unroll
        for (int mi = 0; mi < 2; mi++)
            af[mi] = *(const short8*)&As[(wr * 32 + mi * 16 + cl) * 32 + fs * 8];
        #pragma unroll
        for (int ni = 0; ni < 2; ni++)
            bf[ni] = *(const short8*)&Bs[(wc * 32 + ni * 16 + cl) * 32 + fs * 8];
        #pragma unroll
        for (int mi = 0; mi < 2; mi++)
            #pragma unroll
            for (int ni = 0; ni < 2; ni++)
                acc[mi][ni] = __builtin_amdgcn_mfma_f32_16x16x32_bf16(
                    af[mi], bf[ni], acc[mi][ni], 0, 0, 0);
    }
    #pragma unroll
    for (int mi = 0; mi < 2; mi++)
        #pragma unroll
        for (int ni = 0; ni < 2; ni++)
            #pragma unroll
            for (int r = 0; r < 4; r++)
                Co[(size_t)(row0 + wr * 32 + mi * 16 + quad * 4 + r) * CC
                   + col0 + wc * 32 + ni * 16 + cl] = acc[mi][ni][r];
}

// ---------------------------------------------------------------------------
extern "C" void kernel_launch(void* const* d_in, const int* in_sizes, int n_in,
                              void* d_out, int out_size, void* d_ws, size_t ws_size,
                              hipStream_t stream)
{
    (void)in_sizes; (void)n_in; (void)out_size; (void)ws_size;
    const float* x      = (const float*)d_in[0];
    const float* stm    = (const float*)d_in[1];
    // d_in[2] = long_q: unused (output slice only covers query rows >= L+S)
    const float* long_k = (const float*)d_in[3];
    const float* long_v = (const float*)d_in[4];
    const float* w_attn = (const float*)d_in[5];
    const float* w_proj = (const float*)d_in[6];
    float* out = (float*)d_out;

    short* Xb   = (short*)d_ws;                 // 3,145,728
    short* WaT  = Xb   + (size_t)3145728;       // 3,145,728
    short* WpT  = WaT  + (size_t)3145728;       // 1,048,576
    short* Qb   = WpT  + (size_t)1048576;       // 2,097,152
    short* Kb   = Qb   + (size_t)2097152;       // 5,242,880
    short* Vtr  = Kb   + (size_t)5242880;       // 5,242,880
    short* Yb   = Vtr  + (size_t)5242880;       // 2,097,152
    float* RTab = (float*)(Yb + (size_t)2097152);     // 98,304 floats
    short* Opart = (short*)(RTab + 98304);            // 8,388,608 shorts (4 pieces)
    float* Lpart = (float*)(Opart + (size_t)8388608); // 131,072 floats

    // MEASUREMENT (round 8): prep_all, attn_combine, proj_gemm each launched
    // TWICE (all idempotent — pure functions of their inputs; stream-
    // serialized). delta-total vs r6/r7 baseline = prep + combine + proj.
    // qkv known (28.6 us, r7); attn known (46.1-46.4 us, top-5).
    prep_all<<<7872, 256, 0, stream>>>(x, stm, w_attn, w_proj, long_k, long_v,
                                       Xb, WaT, WpT, Kb, Vtr, RTab);
    prep_all<<<7872, 256, 0, stream>>>(x, stm, w_attn, w_proj, long_k, long_v,
                                       Xb, WaT, WpT, Kb, Vtr, RTab);

    qkv_gemm<<<dim3(48, 12, 2), 256, 0, stream>>>(Xb, WaT, RTab, Qb, Kb, Vtr);

    attn_mfma<<<dim3(32, 8, 4), 256, 0, stream>>>(Qb, Kb, Vtr, Opart, Lpart);

    attn_combine<<<1024, 256, 0, stream>>>(Opart, Lpart, Yb);
    attn_combine<<<1024, 256, 0, stream>>>(Opart, Lpart, Yb);

    proj_gemm<<<dim3(16, 32), 256, 0, stream>>>(Yb, WpT, out);
    proj_gemm<<<dim3(16, 32), 256, 0, stream>>>(Yb, WpT, out);
}

// Round 9
// 220.748 us; speedup vs baseline: 1.0263x; 1.0263x over previous
//
#include <hip/hip_runtime.h>
#include <math.h>

// Problem constants
#define BB 2
#define TT 1024
#define CC 1024
#define HH 16
#define HD 64
#define SS 512
#define LL 1024
#define ST 1536   // S+T
#define MM 2560   // L+S+T
#define C3 3072   // 3*C

typedef __attribute__((ext_vector_type(8))) short short8;    // 8 bf16 (4 VGPRs)
typedef __attribute__((ext_vector_type(4))) short short4v;
typedef __attribute__((ext_vector_type(4))) float floatx4;

__device__ __forceinline__ unsigned short f2bf(float f) {
    union { float f; unsigned u; } v; v.f = f;
    unsigned r = v.u + 0x7fffu + ((v.u >> 16) & 1u);   // RNE
    return (unsigned short)(r >> 16);
}
__device__ __forceinline__ float bf2f(short s) {
    union { unsigned u; float f; } v;
    v.u = ((unsigned)(unsigned short)s) << 16;
    return v.f;
}

// async global->LDS, 16B per lane; LDS side is wave-uniform base + lane*16
__device__ __forceinline__ void gl_lds16(const short* g, short* l) {
    __builtin_amdgcn_global_load_lds(
        (const __attribute__((address_space(1))) void*)g,
        (__attribute__((address_space(3))) void*)l,
        16, 0, 0);
}

// ---------------------------------------------------------------------------
// prep_all: all independent prep work in ONE launch, partitioned by blockIdx.
//   [0,3072)    cast_xcat   xcat fp32 -> Xb bf16
//   [3072,6144) wtrans(w_attn)  [1024][3072] -> WaT [3072][1024] bf16
//   [6144,7168) wtrans(w_proj)  [1024][1024] -> WpT [1024][1024] bf16
//   [7168,7360) rope_table
//   [7360,7872) long_k -> Kb rows [0,L), long_v -> Vtr [bh][d][j] transposed
//   Measured r8 (with combine+proj): all three sum to ~26-30 us — near BW floor.
// ---------------------------------------------------------------------------
__global__ __launch_bounds__(256)
void prep_all(const float* __restrict__ x, const float* __restrict__ stm,
              const float* __restrict__ w_attn, const float* __restrict__ w_proj,
              const float* __restrict__ lk, const float* __restrict__ lv,
              short* __restrict__ Xb, short* __restrict__ WaT,
              short* __restrict__ WpT, short* __restrict__ Kg,
              short* __restrict__ Vt, float* __restrict__ tab)
{
    __shared__ __align__(16) char smem[9216];
    const int blk = blockIdx.x;
    const int t = threadIdx.x;

    if (blk < 3072) {
        // ---- cast_xcat ----
        const int idx = blk * 256 + t;
        const int rg  = idx >> 8;
        const int c   = (idx & 255) << 2;
        const int b   = rg >= ST;
        const int r   = rg - b * ST;
        const float* src = (r < SS) ? (stm + ((size_t)b * SS + r) * CC + c)
                                    : (x   + ((size_t)b * TT + (r - SS)) * CC + c);
        float4 v = *(const float4*)src;
        short4v o;
        o.x = (short)f2bf(v.x); o.y = (short)f2bf(v.y);
        o.z = (short)f2bf(v.z); o.w = (short)f2bf(v.w);
        *(short4v*)(Xb + (size_t)rg * CC + c) = o;
    } else if (blk < 7168) {
        // ---- weight transpose+cast ----
        const bool isA = blk < 6144;
        const int bx = isA ? (blk - 3072) : (blk - 6144);
        const int nblk = isA ? 96 : 32;
        const int Nd = isA ? C3 : CC;
        const float* W = isA ? w_attn : w_proj;
        short* WT = isA ? WaT : WpT;
        const int n0 = (bx % nblk) * 32, k0 = (bx / nblk) * 32;
        float (*Tl)[33] = (float(*)[33])smem;
        const int r = t >> 3, c4 = (t & 7) << 2;
        float4 v = *(const float4*)(W + (size_t)(k0 + r) * Nd + n0 + c4);
        Tl[r][c4 + 0] = v.x; Tl[r][c4 + 1] = v.y;
        Tl[r][c4 + 2] = v.z; Tl[r][c4 + 3] = v.w;
        __syncthreads();
        short4v o;
        o.x = (short)f2bf(Tl[c4 + 0][r]); o.y = (short)f2bf(Tl[c4 + 1][r]);
        o.z = (short)f2bf(Tl[c4 + 2][r]); o.w = (short)f2bf(Tl[c4 + 3][r]);
        *(short4v*)(WT + (size_t)(n0 + r) * CC + k0 + c4) = o;
    } else if (blk < 7360) {
        // ---- rope table ----
        const int idx = (blk - 7168) * 256 + t;   // < 49152
        const int r = idx >> 5, e = idx & 31;
        const float inv = powf(10000.0f, -(float)e * (1.0f / 32.0f));
        float sn, cs;
        sincosf((float)r * inv, &sn, &cs);
        tab[idx * 2] = cs;
        tab[idx * 2 + 1] = sn;
    } else {
        // ---- long_k -> Kb (cast), long_v -> Vtr (cast + transpose) ----
        const int bx = blk - 7360;                 // < 512
        const int bh = bx >> 4, j0 = (bx & 15) * 64;
        const int b = bh >> 4, h = bh & 15;
        short (*Tl)[72] = (short(*)[72])smem;
        const int jr = t >> 2, c16 = (t & 3) << 4;
        const size_t si = (((size_t)b * LL + j0 + jr) * HH + h) * HD + c16;
        short kk[16], vv[16];
        #pragma unroll
        for (int u = 0; u < 4; u++) {
            float4 kv = *(const float4*)(lk + si + 4 * u);
            float4 vf = *(const float4*)(lv + si + 4 * u);
            kk[4*u+0] = (short)f2bf(kv.x); kk[4*u+1] = (short)f2bf(kv.y);
            kk[4*u+2] = (short)f2bf(kv.z); kk[4*u+3] = (short)f2bf(kv.w);
            vv[4*u+0] = (short)f2bf(vf.x); vv[4*u+1] = (short)f2bf(vf.y);
            vv[4*u+2] = (short)f2bf(vf.z); vv[4*u+3] = (short)f2bf(vf.w);
        }
        short* kdst = Kg + ((size_t)bh * MM + j0 + jr) * HD + c16;
        *(short8*)kdst       = *(short8*)&kk[0];
        *(short8*)(kdst + 8) = *(short8*)&kk[8];
        #pragma unroll
        for (int u = 0; u < 16; u++) Tl[jr][c16 + u] = vv[u];
        __syncthreads();
        const int r = t >> 2, c = t & 3;    // r = d index, c = j chunk
        short o0[8], o1[8];
        #pragma unroll
        for (int u = 0; u < 8; u++) {
            o0[u] = Tl[c * 16 + u][r];
            o1[u] = Tl[c * 16 + 8 + u][r];
        }
        short* vdst = Vt + ((size_t)bh * HD + r) * MM + j0 + c * 16;
        *(short8*)vdst       = *(short8*)&o0[0];
        *(short8*)(vdst + 8) = *(short8*)&o1[0];
    }
}

// ---------------------------------------------------------------------------
// Kernel: qkv MFMA GEMM — r6 structure (128x64 tiles, LDS union, 4 blk/CU).
//   Measured r7: ~28.6 us = ~675 TF — near structural ceiling for this size.
// ---------------------------------------------------------------------------
__global__ __launch_bounds__(256)
void qkv_gemm(const short* __restrict__ A, const short* __restrict__ Bt,
              const float* __restrict__ RT,
              short* __restrict__ Qo, short* __restrict__ Ko, short* __restrict__ Vo)
{
    __shared__ __align__(16) short U[12288];   // 24 KB
    short* As = U;            // [128][64] shorts  (K-loop)
    short* Bs = U + 8192;     // [64][64]  shorts  (K-loop)
    short* Et = U;            // epilogue overlay: [128][68] (Q/K) or [64][132] (V)

    const int b = blockIdx.z;
    const int row0 = blockIdx.y * 128, col0 = blockIdx.x * 64;
    const int tid = threadIdx.x;
    const int w = tid >> 6, l = tid & 63, quad = l >> 4, cl = l & 15;
    const int wr = w >> 1, wc = w & 1;   // wave tile: rows wr*64..+64, cols wc*32..+32

    const int reg  = col0 >> 10;
    const bool hasQ = (row0 >= SS);
    if (reg == 0 && !hasQ) return;

    // staging lane assignment (r4-verified pattern)
    const int srow8 = l >> 3;            // 0..7: row within 8-row issue group
    const int sl8   = l & 7;             // 16B slot within the 64-short row
    const int ch0   = (sl8 - (srow8 >> 1)) & 7;
    const int ch1   = (sl8 - 4 - (srow8 >> 1)) & 7;
    // A: wave w stages rows [w*32, w*32+32), 4 issues of 8 rows
    const short* gA = A + ((size_t)b * ST + row0 + w * 32 + srow8) * CC;
    short* lA = &As[(w * 32) * 64 + l * 8];
    // B: wave w stages rows [w*16, w*16+16), 2 issues of 8 rows
    const short* gB = Bt + ((size_t)(col0 + w * 16 + srow8)) * CC;
    short* lB = &Bs[(w * 16) * 64 + l * 8];

    floatx4 acc[4][2];
    #pragma unroll
    for (int mi = 0; mi < 4; mi++)
        #pragma unroll
        for (int ni = 0; ni < 2; ni++) acc[mi][ni] = (floatx4){0.f, 0.f, 0.f, 0.f};

    for (int k0 = 0; k0 < CC; k0 += 64) {
        __syncthreads();
        gl_lds16(gA + k0 + ch0 * 8,                     lA);
        gl_lds16(gA + (size_t)8  * CC + k0 + ch1 * 8,   lA + 512);
        gl_lds16(gA + (size_t)16 * CC + k0 + ch0 * 8,   lA + 1024);
        gl_lds16(gA + (size_t)24 * CC + k0 + ch1 * 8,   lA + 1536);
        gl_lds16(gB + k0 + ch0 * 8,                     lB);
        gl_lds16(gB + (size_t)8  * CC + k0 + ch1 * 8,   lB + 512);
        __syncthreads();
        #pragma unroll
        for (int ks = 0; ks < 2; ks++) {
            const int slot = (ks * 4 + quad + (cl >> 1)) & 7;
            short8 af[4], bf[2];
            #pragma unroll
            for (int mi = 0; mi < 4; mi++)
                af[mi] = *(const short8*)&As[(wr * 64 + mi * 16 + cl) * 64 + slot * 8];
            #pragma unroll
            for (int ni = 0; ni < 2; ni++)
                bf[ni] = *(const short8*)&Bs[(wc * 32 + ni * 16 + cl) * 64 + slot * 8];
            #pragma unroll
            for (int mi = 0; mi < 4; mi++)
                #pragma unroll
                for (int ni = 0; ni < 2; ni++)
                    acc[mi][ni] = __builtin_amdgcn_mfma_f32_16x16x32_bf16(
                        af[mi], bf[ni], acc[mi][ni], 0, 0, 0);
        }
    }

    __syncthreads();   // As/Bs dead -> Et overlay becomes safe

    const int hh = (col0 & 1023) >> 6;   // single head per 64-col tile

    #pragma unroll
    for (int ni = 0; ni < 2; ni++) {
        const int c_local = wc * 32 + ni * 16 + cl;   // [0,64) = d within head
        const int e = c_local >> 1;
        #pragma unroll
        for (int mi = 0; mi < 4; mi++) {
            #pragma unroll
            for (int r = 0; r < 4; r++) {
                const int R_local = wr * 64 + mi * 16 + quad * 4 + r;
                const int R = row0 + R_local;
                float v = acc[mi][ni][r];
                if (reg < 2) {
                    const float2 tt = ((const float2*)RT)[R * 32 + e];
                    union { float f; int i; } vu; vu.f = v;
                    const float po = __int_as_float(
                        __builtin_amdgcn_mov_dpp(vu.i, 0xB1, 0xf, 0xf, true));
                    float out = ((cl & 1) == 0) ? (v * tt.x - po * tt.y)
                                                : (po * tt.y + v * tt.x);
                    union { float f; int i; } ou; ou.f = out;
                    const int oo = __builtin_amdgcn_mov_dpp(ou.i, 0xB1, 0xf, 0xf, true);
                    if ((cl & 1) == 0) {
                        unsigned word;
                        asm("v_cvt_pk_bf16_f32 %0, %1, %2"
                            : "=v"(word) : "v"(out), "v"(__int_as_float(oo)));
                        *(unsigned*)&Et[R_local * 68 + c_local] = word;
                    }
                } else {
                    Et[c_local * 132 + R_local] = (short)f2bf(v);
                }
            }
        }
    }
    __syncthreads();

    if (reg < 2) {
        short* dstb = (reg == 0)
            ? Qo + (((size_t)b * HH + hh) * TT + (row0 - SS)) * HD
            : Ko + (((size_t)b * HH + hh) * MM + LL + row0) * HD;
        #pragma unroll
        for (int it = 0; it < 4; it++) {
            const int idx = it * 2048 + tid * 8;   // r*64 + d, r<128
            const int r = idx >> 6, d = idx & 63;
            short4v v0 = *(const short4v*)&Et[r * 68 + d];
            short4v v1 = *(const short4v*)&Et[r * 68 + d + 4];
            short8 vv;
            #pragma unroll
            for (int u = 0; u < 4; u++) { vv[u] = v0[u]; vv[u + 4] = v1[u]; }
            *(short8*)(dstb + idx) = vv;
        }
    } else {
        #pragma unroll
        for (int it = 0; it < 4; it++) {
            const int idx = it * 2048 + tid * 8;   // d*128 + r0, d<64
            const int d = idx >> 7, r0 = idx & 127;
            short4v v0 = *(const short4v*)&Et[d * 132 + r0];
            short4v v1 = *(const short4v*)&Et[d * 132 + r0 + 4];
            short8 vv;
            #pragma unroll
            for (int u = 0; u < 4; u++) { vv[u] = v0[u]; vv[u + 4] = v1[u]; }
            *(short8*)(Vo + (((size_t)b * HH + hh) * HD + d) * MM + LL + row0 + r0) = vv;
        }
    }
}

// ---------------------------------------------------------------------------
// Kernel: MFMA flash attention v3.2 (round-9): single-buffer PREFETCH.
//   Mechanism: the old loop issued gl_lds16 then immediately drained
//   (syncthreads = vmcnt(0)+barrier) — full load latency exposed per tile.
//   New: QK consumes K from LDS; the 8 V fragments are copied to REGISTERS
//   (+32 VGPR); lgkmcnt(0); barrier (buffer now free in ALL waves); issue
//   tile t+1's gl_lds16 BEFORE softmax. Load latency hides under softmax +
//   P round-trip + PV; next iteration's vmcnt(0) drain is then cheap.
//   r1's failure modes avoided: LDS unchanged 34816 (4 blk/CU), 2 barriers
//   per tile, 1-tile-deep prefetch, MFMA order bit-identical.
//   Race safety: each wave drains its OWN lgkm before barrier-2 => all
//   K/V reads retired before any wave overwrites; each wave drains its
//   OWN vmcnt inside barrier-1's syncthreads => tile landed.
//   VGPR 64 -> ~128 = exactly 4 waves/SIMD (launch_bounds(256,4)).
//   Keeps r7's setprio (measured neutral-positive).
// ---------------------------------------------------------------------------
#define PSP 72
#define PSW (32 * PSP)
#define VS_OFF 4096
#define PS_OFF 8192
__global__ __launch_bounds__(256, 4)
void attn_mfma(const short* __restrict__ Qg, const short* __restrict__ Kg,
               const short* __restrict__ Vt, short* __restrict__ Op,
               float* __restrict__ Lp)
{
    // L layout (shorts): [0,4096) Ks [key][d] | [4096,8192) Vs [d][key]
    //                    [8192,17408) Ps 4 waves x [32 q][72]
    // Ys (post-loop) = L[0 .. 128*68) overlapping Ks/Vs/Ps-head explicitly.
    __shared__ __align__(16) short L[17408];

    const int bh = blockIdx.x;
    const int q0 = (7 - blockIdx.y) * 128;   // heavy blocks dispatch first
    const int piece = blockIdx.z;            // 0..3 split-K
    const int tid = threadIdx.x, w = tid >> 6, l = tid & 63;
    const int quad = l >> 4, cl = l & 15;

    // Q fragments: two 16-q groups per wave
    short8 qa[2][2];
    #pragma unroll
    for (int g = 0; g < 2; g++) {
        const short* qptr = Qg + ((size_t)bh * TT + q0 + w * 32 + g * 16 + cl) * HD + quad * 8;
        qa[g][0] = *(const short8*)qptr;
        qa[g][1] = *(const short8*)(qptr + 32);
    }

    floatx4 o[2][4];
    float rs[2][4];
    #pragma unroll
    for (int g = 0; g < 2; g++)
        #pragma unroll
        for (int r = 0; r < 4; r++) {
            rs[g][r] = 0.f;
            o[g][r] = (floatx4){0.f, 0.f, 0.f, 0.f};
        }

    // async staging lane assignment (verified r5/r6)
    const int srow_lo = l >> 3;
    const int sslot  = l & 7;
    const int ch0 = (sslot - (srow_lo >> 1)) & 7;
    const int ch1 = (sslot - (4 + (srow_lo >> 1))) & 7;
    const int rowi0 = w * 16 + srow_lo;
    const int rowi1 = w * 16 + 8 + srow_lo;
    const short* kgb = Kg + (size_t)bh * MM * HD;
    const short* vbase = Vt + (size_t)bh * HD * MM;
    short* ldsK0 = &L[(w * 16) * 64];
    short* ldsK1 = &L[(w * 16 + 8) * 64];
    short* ldsV0 = &L[VS_OFF + (w * 16) * 64];
    short* ldsV1 = &L[VS_OFF + (w * 16 + 8) * 64];

    const int fsA = (quad + (cl >> 1)) & 7;
    const int fsB = (quad + 4 + (cl >> 1)) & 7;
    const int psA = (quad + 2 * cl) & 7;       // P dewizzle: slot=(chunk+2*row)&7
    const int psB = (quad + 4 + 2 * cl) & 7;

    const int ntiles = (LL + SS + q0) / 64 + 2;
    const int t_begin = piece * ntiles / 4;
    const int t_end   = (piece + 1) * ntiles / 4;

// issue tile tt's 4 async loads (wave-private LDS rows)
#define STAGE(tt) do {                                                        \
    const int jj = (tt) * 64;                                                 \
    gl_lds16(kgb + (size_t)(jj + rowi0) * HD + ch0 * 8, ldsK0);               \
    gl_lds16(kgb + (size_t)(jj + rowi1) * HD + ch1 * 8, ldsK1);               \
    gl_lds16(vbase + (size_t)rowi0 * MM + jj + ch0 * 8, ldsV0);               \
    gl_lds16(vbase + (size_t)rowi1 * MM + jj + ch1 * 8, ldsV1);               \
} while (0)

    STAGE(t_begin);

    for (int t = t_begin; t < t_end; t++) {
        const int j0 = t * 64;
        __syncthreads();   // own vmcnt drained inside -> tile t landed, all waves

        // ---- S = Q.K^T for both q-groups (K frags transient from LDS) ----
        __builtin_amdgcn_s_setprio(1);
        floatx4 s[2][4];
        #pragma unroll
        for (int ks = 0; ks < 4; ks++) {
            const int krow = ks * 16 + cl;
            short8 kf0 = *(const short8*)&L[krow * 64 + fsA * 8];
            short8 kf1 = *(const short8*)&L[krow * 64 + fsB * 8];
            #pragma unroll
            for (int g = 0; g < 2; g++) {
                floatx4 z = (floatx4){0.f, 0.f, 0.f, 0.f};
                z = __builtin_amdgcn_mfma_f32_16x16x32_bf16(qa[g][0], kf0, z, 0, 0, 0);
                z = __builtin_amdgcn_mfma_f32_16x16x32_bf16(qa[g][1], kf1, z, 0, 0, 0);
                s[g][ks] = z;
            }
        }
        __builtin_amdgcn_s_setprio(0);

        // ---- V fragments -> registers (frees the K/V buffer) ----
        short8 vf[4][2];
        #pragma unroll
        for (int nt = 0; nt < 4; nt++) {
            const int drow = nt * 16 + cl;
            vf[nt][0] = *(const short8*)&L[VS_OFF + drow * 64 + fsA * 8];
            vf[nt][1] = *(const short8*)&L[VS_OFF + drow * 64 + fsB * 8];
        }
        __builtin_amdgcn_s_waitcnt(0xc07f);   // lgkmcnt(0): all K/V reads retired
        __syncthreads();                       // buffer free across all waves

        if (t + 1 < t_end) STAGE(t + 1);       // latency hides under softmax+PV

        // ---- no-max softmax: p = exp(s/8); per-lane partial sums ----
        const bool tailzone = (t >= ntiles - 2);
        #pragma unroll
        for (int g = 0; g < 2; g++) {
            const int qgb = LL + SS + q0 + w * 32 + g * 16;
            #pragma unroll
            for (int ks = 0; ks < 4; ks++) {
                #pragma unroll
                for (int r = 0; r < 4; r++) {
                    float sv = s[g][ks][r] * 0.125f;
                    if (tailzone && (j0 + ks * 16 + cl > qgb + quad * 4 + r))
                        sv = -INFINITY;
                    const float p = __expf(sv);
                    rs[g][r] += p;
                    const int qrw = quad * 4 + r;
                    const int slot = (ks * 2 + (cl >> 3) + 2 * qrw) & 7;
                    L[PS_OFF + w * PSW + (g * 16 + qrw) * PSP + slot * 8 + (cl & 7)] =
                        (short)f2bf(p);
                }
            }
        }

        // wave-private LDS write->read: drain ds queue, pin ordering
        __builtin_amdgcn_s_waitcnt(0xc07f);   // lgkmcnt(0)
        __builtin_amdgcn_wave_barrier();

        // ---- O += P.V (V from registers) ----
        short8 pf[2][2];
        #pragma unroll
        for (int g = 0; g < 2; g++) {
            pf[g][0] = *(const short8*)&L[PS_OFF + w * PSW + (g * 16 + cl) * PSP + psA * 8];
            pf[g][1] = *(const short8*)&L[PS_OFF + w * PSW + (g * 16 + cl) * PSP + psB * 8];
        }
        __builtin_amdgcn_s_setprio(1);
        #pragma unroll
        for (int nt = 0; nt < 4; nt++) {
            #pragma unroll
            for (int g = 0; g < 2; g++) {
                o[g][nt] = __builtin_amdgcn_mfma_f32_16x16x32_bf16(pf[g][0], vf[nt][0], o[g][nt], 0, 0, 0);
                o[g][nt] = __builtin_amdgcn_mfma_f32_16x16x32_bf16(pf[g][1], vf[nt][1], o[g][nt], 0, 0, 0);
            }
        }
        __builtin_amdgcn_s_setprio(0);
    }
#undef STAGE

    // ---- deferred l reduction (only shuffles in the kernel) ----
    #pragma unroll
    for (int g = 0; g < 2; g++)
        #pragma unroll
        for (int r = 0; r < 4; r++) {
            float t2 = rs[g][r];
            t2 += __shfl_xor(t2, 1);
            t2 += __shfl_xor(t2, 2);
            t2 += __shfl_xor(t2, 4);
            t2 += __shfl_xor(t2, 8);
            if (cl == 0)
                Lp[piece * 32768 + bh * 1024 + q0 + w * 32 + g * 16 + quad * 4 + r] = t2;
        }

    // ---- stage raw partial O -> coalesced store (Ys = L[0..8704), explicit) ----
    __syncthreads();   // all waves done reading Ks/Vs/Ps
    #pragma unroll
    for (int g = 0; g < 2; g++)
        #pragma unroll
        for (int r = 0; r < 4; r++) {
            const int ql = w * 32 + g * 16 + quad * 4 + r;
            #pragma unroll
            for (int nt = 0; nt < 4; nt++)
                L[ql * 68 + nt * 16 + cl] = (short)f2bf(o[g][nt][r]);
        }
    __syncthreads();
    short* ob = Op + ((size_t)(piece * 32 + bh) * 1024 + q0) * 64;
    #pragma unroll
    for (int it = 0; it < 4; it++) {
        const int idx = it * 2048 + tid * 8;   // q*64 + d, q<128
        const int q = idx >> 6, d = idx & 63;
        short4v v0 = *(const short4v*)&L[q * 68 + d];
        short4v v1 = *(const short4v*)&L[q * 68 + d + 4];
        short8 vv;
        #pragma unroll
        for (int u = 0; u < 4; u++) { vv[u] = v0[u]; vv[u + 4] = v1[u]; }
        *(short8*)(ob + idx) = vv;
    }
}

// ---------------------------------------------------------------------------
// Kernel: combine 4 split-K pieces (raw O sums + l sums) -> Yatt bf16
// ---------------------------------------------------------------------------
__global__ __launch_bounds__(256)
void attn_combine(const short* __restrict__ Op, const float* __restrict__ Lp,
                  short* __restrict__ Yatt)
{
    const int idx = blockIdx.x * 256 + threadIdx.x;   // < 262144
    const int row = idx >> 3;            // bh*1024 + q
    const int seg = (idx & 7) << 3;
    const float lsum = Lp[row] + Lp[32768 + row] + Lp[65536 + row] + Lp[98304 + row];
    const float inv = 1.0f / lsum;
    float acc[8] = {0.f, 0.f, 0.f, 0.f, 0.f, 0.f, 0.f, 0.f};
    #pragma unroll
    for (int p = 0; p < 4; p++) {
        short8 v = *(const short8*)(Op + ((size_t)(p * 32768) + row) * 64 + seg);
        #pragma unroll
        for (int u = 0; u < 8; u++) acc[u] += bf2f(v[u]);
    }
    short8 o8;
    #pragma unroll
    for (int u = 0; u < 8; u++) o8[u] = (short)f2bf(acc[u] * inv);
    const int bh = row >> 10, q = row & 1023;
    const int b = bh >> 4, h = bh & 15;
    *(short8*)(Yatt + ((size_t)b * TT + q) * CC + h * 64 + seg) = o8;
}

// ---------------------------------------------------------------------------
// Kernel: proj MFMA GEMM, 64x64 tiles (512 blocks -> 2/CU) — r4-proven
// version. 4 waves 2x2, each wave 32x32. Async staging.
// ---------------------------------------------------------------------------
__global__ __launch_bounds__(256)
void proj_gemm(const short* __restrict__ A, const short* __restrict__ Bt,
               float* __restrict__ Co)
{
    __shared__ short As[64 * 32];
    __shared__ short Bs[64 * 32];
    const int row0 = blockIdx.y * 64, col0 = blockIdx.x * 64;
    const int tid = threadIdx.x;
    const int w = tid >> 6, l = tid & 63, quad = l >> 4, cl = l & 15;
    const int wr = w >> 1, wc = w & 1;

    const int srow = tid >> 2;               // 0..63
    const int schunk = ((tid & 3) - ((srow & 15) >> 1)) & 3;
    const short* gA = A + (size_t)(row0 + srow) * CC + schunk * 8;
    const short* gB = Bt + (size_t)(col0 + srow) * CC + schunk * 8;
    short* lA = &As[tid * 8];
    short* lB = &Bs[tid * 8];

    const int fs = (quad + (cl >> 1)) & 3;

    floatx4 acc[2][2];
    #pragma unroll
    for (int mi = 0; mi < 2; mi++)
        #pragma unroll
        for (int ni = 0; ni < 2; ni++) acc[mi][ni] = (floatx4){0.f, 0.f, 0.f, 0.f};

    for (int k0 = 0; k0 < CC; k0 += 32) {
        __syncthreads();
        gl_lds16(gA + k0, lA);
        gl_lds16(gB + k0, lB);
        __syncthreads();
        short8 af[2], bf[2];
        #pragma unroll
        for (int mi = 0; mi < 2; mi++)
            af[mi] = *(const short8*)&As[(wr * 32 + mi * 16 + cl) * 32 + fs * 8];
        #pragma unroll
        for (int ni = 0; ni < 2; ni++)
            bf[ni] = *(const short8*)&Bs[(wc * 32 + ni * 16 + cl) * 32 + fs * 8];
        #pragma unroll
        for (int mi = 0; mi < 2; mi++)
            #pragma unroll
            for (int ni = 0; ni < 2; ni++)
                acc[mi][ni] = __builtin_amdgcn_mfma_f32_16x16x32_bf16(
                    af[mi], bf[ni], acc[mi][ni], 0, 0, 0);
    }
    #pragma unroll
    for (int mi = 0; mi < 2; mi++)
        #pragma unroll
        for (int ni = 0; ni < 2; ni++)
            #pragma unroll
            for (int r = 0; r < 4; r++)
                Co[(size_t)(row0 + wr * 32 + mi * 16 + quad * 4 + r) * CC
                   + col0 + wc * 32 + ni * 16 + cl] = acc[mi][ni][r];
}

// ---------------------------------------------------------------------------
extern "C" void kernel_launch(void* const* d_in, const int* in_sizes, int n_in,
                              void* d_out, int out_size, void* d_ws, size_t ws_size,
                              hipStream_t stream)
{
    (void)in_sizes; (void)n_in; (void)out_size; (void)ws_size;
    const float* x      = (const float*)d_in[0];
    const float* stm    = (const float*)d_in[1];
    // d_in[2] = long_q: unused (output slice only covers query rows >= L+S)
    const float* long_k = (const float*)d_in[3];
    const float* long_v = (const float*)d_in[4];
    const float* w_attn = (const float*)d_in[5];
    const float* w_proj = (const float*)d_in[6];
    float* out = (float*)d_out;

    short* Xb   = (short*)d_ws;                 // 3,145,728
    short* WaT  = Xb   + (size_t)3145728;       // 3,145,728
    short* WpT  = WaT  + (size_t)3145728;       // 1,048,576
    short* Qb   = WpT  + (size_t)1048576;       // 2,097,152
    short* Kb   = Qb   + (size_t)2097152;       // 5,242,880
    short* Vtr  = Kb   + (size_t)5242880;       // 5,242,880
    short* Yb   = Vtr  + (size_t)5242880;       // 2,097,152
    float* RTab = (float*)(Yb + (size_t)2097152);     // 98,304 floats
    short* Opart = (short*)(RTab + 98304);            // 8,388,608 shorts (4 pieces)
    float* Lpart = (float*)(Opart + (size_t)8388608); // 131,072 floats

    prep_all<<<7872, 256, 0, stream>>>(x, stm, w_attn, w_proj, long_k, long_v,
                                       Xb, WaT, WpT, Kb, Vtr, RTab);

    qkv_gemm<<<dim3(48, 12, 2), 256, 0, stream>>>(Xb, WaT, RTab, Qb, Kb, Vtr);

    attn_mfma<<<dim3(32, 8, 4), 256, 0, stream>>>(Qb, Kb, Vtr, Opart, Lpart);
    attn_combine<<<1024, 256, 0, stream>>>(Opart, Lpart, Yb);

    proj_gemm<<<dim3(16, 32), 256, 0, stream>>>(Yb, WpT, out);
}

// Round 10
// 194.294 us; speedup vs baseline: 1.1661x; 1.1362x over previous
//
#include <hip/hip_runtime.h>
#include <math.h>

// Problem constants
#define BB 2
#define TT 1024
#define CC 1024
#define HH 16
#define HD 64
#define SS 512
#define LL 1024
#define ST 1536   // S+T
#define MM 2560   // L+S+T
#define C3 3072   // 3*C

typedef __attribute__((ext_vector_type(8))) short short8;    // 8 bf16 (4 VGPRs)
typedef __attribute__((ext_vector_type(4))) short short4v;
typedef __attribute__((ext_vector_type(4))) float floatx4;

__device__ __forceinline__ unsigned short f2bf(float f) {
    union { float f; unsigned u; } v; v.f = f;
    unsigned r = v.u + 0x7fffu + ((v.u >> 16) & 1u);   // RNE
    return (unsigned short)(r >> 16);
}
__device__ __forceinline__ float bf2f(short s) {
    union { unsigned u; float f; } v;
    v.u = ((unsigned)(unsigned short)s) << 16;
    return v.f;
}

// async global->LDS, 16B per lane; LDS side is wave-uniform base + lane*16
__device__ __forceinline__ void gl_lds16(const short* g, short* l) {
    __builtin_amdgcn_global_load_lds(
        (const __attribute__((address_space(1))) void*)g,
        (__attribute__((address_space(3))) void*)l,
        16, 0, 0);
}

// ---------------------------------------------------------------------------
// prep_all: all independent prep work in ONE launch, partitioned by blockIdx.
//   [0,3072)    cast_xcat   xcat fp32 -> Xb bf16
//   [3072,6144) wtrans(w_attn)  [1024][3072] -> WaT [3072][1024] bf16
//   [6144,7168) wtrans(w_proj)  [1024][1024] -> WpT [1024][1024] bf16
//   [7168,7360) rope_table
//   [7360,7872) long_k -> Kb rows [0,L), long_v -> Vtr [bh][d][j] transposed
//   Measured r8: prep+combine+proj sum to ~26-30 us — near BW floors.
// ---------------------------------------------------------------------------
__global__ __launch_bounds__(256)
void prep_all(const float* __restrict__ x, const float* __restrict__ stm,
              const float* __restrict__ w_attn, const float* __restrict__ w_proj,
              const float* __restrict__ lk, const float* __restrict__ lv,
              short* __restrict__ Xb, short* __restrict__ WaT,
              short* __restrict__ WpT, short* __restrict__ Kg,
              short* __restrict__ Vt, float* __restrict__ tab)
{
    __shared__ __align__(16) char smem[9216];
    const int blk = blockIdx.x;
    const int t = threadIdx.x;

    if (blk < 3072) {
        // ---- cast_xcat ----
        const int idx = blk * 256 + t;
        const int rg  = idx >> 8;
        const int c   = (idx & 255) << 2;
        const int b   = rg >= ST;
        const int r   = rg - b * ST;
        const float* src = (r < SS) ? (stm + ((size_t)b * SS + r) * CC + c)
                                    : (x   + ((size_t)b * TT + (r - SS)) * CC + c);
        float4 v = *(const float4*)src;
        short4v o;
        o.x = (short)f2bf(v.x); o.y = (short)f2bf(v.y);
        o.z = (short)f2bf(v.z); o.w = (short)f2bf(v.w);
        *(short4v*)(Xb + (size_t)rg * CC + c) = o;
    } else if (blk < 7168) {
        // ---- weight transpose+cast ----
        const bool isA = blk < 6144;
        const int bx = isA ? (blk - 3072) : (blk - 6144);
        const int nblk = isA ? 96 : 32;
        const int Nd = isA ? C3 : CC;
        const float* W = isA ? w_attn : w_proj;
        short* WT = isA ? WaT : WpT;
        const int n0 = (bx % nblk) * 32, k0 = (bx / nblk) * 32;
        float (*Tl)[33] = (float(*)[33])smem;
        const int r = t >> 3, c4 = (t & 7) << 2;
        float4 v = *(const float4*)(W + (size_t)(k0 + r) * Nd + n0 + c4);
        Tl[r][c4 + 0] = v.x; Tl[r][c4 + 1] = v.y;
        Tl[r][c4 + 2] = v.z; Tl[r][c4 + 3] = v.w;
        __syncthreads();
        short4v o;
        o.x = (short)f2bf(Tl[c4 + 0][r]); o.y = (short)f2bf(Tl[c4 + 1][r]);
        o.z = (short)f2bf(Tl[c4 + 2][r]); o.w = (short)f2bf(Tl[c4 + 3][r]);
        *(short4v*)(WT + (size_t)(n0 + r) * CC + k0 + c4) = o;
    } else if (blk < 7360) {
        // ---- rope table ----
        const int idx = (blk - 7168) * 256 + t;   // < 49152
        const int r = idx >> 5, e = idx & 31;
        const float inv = powf(10000.0f, -(float)e * (1.0f / 32.0f));
        float sn, cs;
        sincosf((float)r * inv, &sn, &cs);
        tab[idx * 2] = cs;
        tab[idx * 2 + 1] = sn;
    } else {
        // ---- long_k -> Kb (cast), long_v -> Vtr (cast + transpose) ----
        const int bx = blk - 7360;                 // < 512
        const int bh = bx >> 4, j0 = (bx & 15) * 64;
        const int b = bh >> 4, h = bh & 15;
        short (*Tl)[72] = (short(*)[72])smem;
        const int jr = t >> 2, c16 = (t & 3) << 4;
        const size_t si = (((size_t)b * LL + j0 + jr) * HH + h) * HD + c16;
        short kk[16], vv[16];
        #pragma unroll
        for (int u = 0; u < 4; u++) {
            float4 kv = *(const float4*)(lk + si + 4 * u);
            float4 vf = *(const float4*)(lv + si + 4 * u);
            kk[4*u+0] = (short)f2bf(kv.x); kk[4*u+1] = (short)f2bf(kv.y);
            kk[4*u+2] = (short)f2bf(kv.z); kk[4*u+3] = (short)f2bf(kv.w);
            vv[4*u+0] = (short)f2bf(vf.x); vv[4*u+1] = (short)f2bf(vf.y);
            vv[4*u+2] = (short)f2bf(vf.z); vv[4*u+3] = (short)f2bf(vf.w);
        }
        short* kdst = Kg + ((size_t)bh * MM + j0 + jr) * HD + c16;
        *(short8*)kdst       = *(short8*)&kk[0];
        *(short8*)(kdst + 8) = *(short8*)&kk[8];
        #pragma unroll
        for (int u = 0; u < 16; u++) Tl[jr][c16 + u] = vv[u];
        __syncthreads();
        const int r = t >> 2, c = t & 3;    // r = d index, c = j chunk
        short o0[8], o1[8];
        #pragma unroll
        for (int u = 0; u < 8; u++) {
            o0[u] = Tl[c * 16 + u][r];
            o1[u] = Tl[c * 16 + 8 + u][r];
        }
        short* vdst = Vt + ((size_t)bh * HD + r) * MM + j0 + c * 16;
        *(short8*)vdst       = *(short8*)&o0[0];
        *(short8*)(vdst + 8) = *(short8*)&o1[0];
    }
}

// ---------------------------------------------------------------------------
// Kernel: qkv MFMA GEMM — r6 structure (128x64 tiles, LDS union, 4 blk/CU).
//   Measured r7: ~28.6 us = ~675 TF — near structural ceiling for this size.
// ---------------------------------------------------------------------------
__global__ __launch_bounds__(256)
void qkv_gemm(const short* __restrict__ A, const short* __restrict__ Bt,
              const float* __restrict__ RT,
              short* __restrict__ Qo, short* __restrict__ Ko, short* __restrict__ Vo)
{
    __shared__ __align__(16) short U[12288];   // 24 KB
    short* As = U;            // [128][64] shorts  (K-loop)
    short* Bs = U + 8192;     // [64][64]  shorts  (K-loop)
    short* Et = U;            // epilogue overlay: [128][68] (Q/K) or [64][132] (V)

    const int b = blockIdx.z;
    const int row0 = blockIdx.y * 128, col0 = blockIdx.x * 64;
    const int tid = threadIdx.x;
    const int w = tid >> 6, l = tid & 63, quad = l >> 4, cl = l & 15;
    const int wr = w >> 1, wc = w & 1;   // wave tile: rows wr*64..+64, cols wc*32..+32

    const int reg  = col0 >> 10;
    const bool hasQ = (row0 >= SS);
    if (reg == 0 && !hasQ) return;

    // staging lane assignment (r4-verified pattern)
    const int srow8 = l >> 3;            // 0..7: row within 8-row issue group
    const int sl8   = l & 7;             // 16B slot within the 64-short row
    const int ch0   = (sl8 - (srow8 >> 1)) & 7;
    const int ch1   = (sl8 - 4 - (srow8 >> 1)) & 7;
    // A: wave w stages rows [w*32, w*32+32), 4 issues of 8 rows
    const short* gA = A + ((size_t)b * ST + row0 + w * 32 + srow8) * CC;
    short* lA = &As[(w * 32) * 64 + l * 8];
    // B: wave w stages rows [w*16, w*16+16), 2 issues of 8 rows
    const short* gB = Bt + ((size_t)(col0 + w * 16 + srow8)) * CC;
    short* lB = &Bs[(w * 16) * 64 + l * 8];

    floatx4 acc[4][2];
    #pragma unroll
    for (int mi = 0; mi < 4; mi++)
        #pragma unroll
        for (int ni = 0; ni < 2; ni++) acc[mi][ni] = (floatx4){0.f, 0.f, 0.f, 0.f};

    for (int k0 = 0; k0 < CC; k0 += 64) {
        __syncthreads();
        gl_lds16(gA + k0 + ch0 * 8,                     lA);
        gl_lds16(gA + (size_t)8  * CC + k0 + ch1 * 8,   lA + 512);
        gl_lds16(gA + (size_t)16 * CC + k0 + ch0 * 8,   lA + 1024);
        gl_lds16(gA + (size_t)24 * CC + k0 + ch1 * 8,   lA + 1536);
        gl_lds16(gB + k0 + ch0 * 8,                     lB);
        gl_lds16(gB + (size_t)8  * CC + k0 + ch1 * 8,   lB + 512);
        __syncthreads();
        #pragma unroll
        for (int ks = 0; ks < 2; ks++) {
            const int slot = (ks * 4 + quad + (cl >> 1)) & 7;
            short8 af[4], bf[2];
            #pragma unroll
            for (int mi = 0; mi < 4; mi++)
                af[mi] = *(const short8*)&As[(wr * 64 + mi * 16 + cl) * 64 + slot * 8];
            #pragma unroll
            for (int ni = 0; ni < 2; ni++)
                bf[ni] = *(const short8*)&Bs[(wc * 32 + ni * 16 + cl) * 64 + slot * 8];
            #pragma unroll
            for (int mi = 0; mi < 4; mi++)
                #pragma unroll
                for (int ni = 0; ni < 2; ni++)
                    acc[mi][ni] = __builtin_amdgcn_mfma_f32_16x16x32_bf16(
                        af[mi], bf[ni], acc[mi][ni], 0, 0, 0);
        }
    }

    __syncthreads();   // As/Bs dead -> Et overlay becomes safe

    const int hh = (col0 & 1023) >> 6;   // single head per 64-col tile

    #pragma unroll
    for (int ni = 0; ni < 2; ni++) {
        const int c_local = wc * 32 + ni * 16 + cl;   // [0,64) = d within head
        const int e = c_local >> 1;
        #pragma unroll
        for (int mi = 0; mi < 4; mi++) {
            #pragma unroll
            for (int r = 0; r < 4; r++) {
                const int R_local = wr * 64 + mi * 16 + quad * 4 + r;
                const int R = row0 + R_local;
                float v = acc[mi][ni][r];
                if (reg < 2) {
                    const float2 tt = ((const float2*)RT)[R * 32 + e];
                    union { float f; int i; } vu; vu.f = v;
                    const float po = __int_as_float(
                        __builtin_amdgcn_mov_dpp(vu.i, 0xB1, 0xf, 0xf, true));
                    float out = ((cl & 1) == 0) ? (v * tt.x - po * tt.y)
                                                : (po * tt.y + v * tt.x);
                    union { float f; int i; } ou; ou.f = out;
                    const int oo = __builtin_amdgcn_mov_dpp(ou.i, 0xB1, 0xf, 0xf, true);
                    if ((cl & 1) == 0) {
                        unsigned word;
                        asm("v_cvt_pk_bf16_f32 %0, %1, %2"
                            : "=v"(word) : "v"(out), "v"(__int_as_float(oo)));
                        *(unsigned*)&Et[R_local * 68 + c_local] = word;
                    }
                } else {
                    Et[c_local * 132 + R_local] = (short)f2bf(v);
                }
            }
        }
    }
    __syncthreads();

    if (reg < 2) {
        short* dstb = (reg == 0)
            ? Qo + (((size_t)b * HH + hh) * TT + (row0 - SS)) * HD
            : Ko + (((size_t)b * HH + hh) * MM + LL + row0) * HD;
        #pragma unroll
        for (int it = 0; it < 4; it++) {
            const int idx = it * 2048 + tid * 8;   // r*64 + d, r<128
            const int r = idx >> 6, d = idx & 63;
            short4v v0 = *(const short4v*)&Et[r * 68 + d];
            short4v v1 = *(const short4v*)&Et[r * 68 + d + 4];
            short8 vv;
            #pragma unroll
            for (int u = 0; u < 4; u++) { vv[u] = v0[u]; vv[u + 4] = v1[u]; }
            *(short8*)(dstb + idx) = vv;
        }
    } else {
        #pragma unroll
        for (int it = 0; it < 4; it++) {
            const int idx = it * 2048 + tid * 8;   // d*128 + r0, d<64
            const int d = idx >> 7, r0 = idx & 127;
            short4v v0 = *(const short4v*)&Et[d * 132 + r0];
            short4v v1 = *(const short4v*)&Et[d * 132 + r0 + 4];
            short8 vv;
            #pragma unroll
            for (int u = 0; u < 4; u++) { vv[u] = v0[u]; vv[u + 4] = v1[u]; }
            *(short8*)(Vo + (((size_t)b * HH + hh) * HD + d) * MM + LL + row0 + r0) = vv;
        }
    }
}

// ---------------------------------------------------------------------------
// Kernel: MFMA flash attention v3.1 + setprio — REVERT to the r7-proven
// version (46.1-46.2 us). r9's register-prefetch variant spilled the V
// fragments to scratch (VGPR_Count stayed 64; FETCH/WRITE exploded to
// 71/98 MB) -> 74.5 us. Attn restructures are 0-for-3 this session; this
// single-buffer structure is the proven local optimum.
//   128 q per block (32 q/wave, two 16-q groups); no-max softmax; deferred
//   l-reduction; split-K x4; setprio around MFMA clusters (>= neutral).
// ---------------------------------------------------------------------------
#define PSP 72
#define PSW (32 * PSP)
#define VS_OFF 4096
#define PS_OFF 8192
__global__ __launch_bounds__(256, 4)
void attn_mfma(const short* __restrict__ Qg, const short* __restrict__ Kg,
               const short* __restrict__ Vt, short* __restrict__ Op,
               float* __restrict__ Lp)
{
    // L layout (shorts): [0,4096) Ks [key][d] | [4096,8192) Vs [d][key]
    //                    [8192,17408) Ps 4 waves x [32 q][72]
    // Ys (post-loop) = L[0 .. 128*68) overlapping Ks/Vs/Ps-head explicitly.
    __shared__ __align__(16) short L[17408];

    const int bh = blockIdx.x;
    const int q0 = (7 - blockIdx.y) * 128;   // heavy blocks dispatch first
    const int piece = blockIdx.z;            // 0..3 split-K
    const int tid = threadIdx.x, w = tid >> 6, l = tid & 63;
    const int quad = l >> 4, cl = l & 15;

    // Q fragments: two 16-q groups per wave
    short8 qa[2][2];
    #pragma unroll
    for (int g = 0; g < 2; g++) {
        const short* qptr = Qg + ((size_t)bh * TT + q0 + w * 32 + g * 16 + cl) * HD + quad * 8;
        qa[g][0] = *(const short8*)qptr;
        qa[g][1] = *(const short8*)(qptr + 32);
    }

    floatx4 o[2][4];
    float rs[2][4];
    #pragma unroll
    for (int g = 0; g < 2; g++)
        #pragma unroll
        for (int r = 0; r < 4; r++) {
            rs[g][r] = 0.f;
            o[g][r] = (floatx4){0.f, 0.f, 0.f, 0.f};
        }

    // async staging lane assignment (verified r5/r6)
    const int srow_lo = l >> 3;
    const int sslot  = l & 7;
    const int ch0 = (sslot - (srow_lo >> 1)) & 7;
    const int ch1 = (sslot - (4 + (srow_lo >> 1))) & 7;
    const int rowi0 = w * 16 + srow_lo;
    const int rowi1 = w * 16 + 8 + srow_lo;
    const short* kgb = Kg + (size_t)bh * MM * HD;
    const short* vbase = Vt + (size_t)bh * HD * MM;
    short* ldsK0 = &L[(w * 16) * 64];
    short* ldsK1 = &L[(w * 16 + 8) * 64];
    short* ldsV0 = &L[VS_OFF + (w * 16) * 64];
    short* ldsV1 = &L[VS_OFF + (w * 16 + 8) * 64];

    const int fsA = (quad + (cl >> 1)) & 7;
    const int fsB = (quad + 4 + (cl >> 1)) & 7;
    const int psA = (quad + 2 * cl) & 7;       // P dewizzle: slot=(chunk+2*row)&7
    const int psB = (quad + 4 + 2 * cl) & 7;

    const int ntiles = (LL + SS + q0) / 64 + 2;
    const int t_begin = piece * ntiles / 4;
    const int t_end   = (piece + 1) * ntiles / 4;

    for (int t = t_begin; t < t_end; t++) {
        const int j0 = t * 64;
        __syncthreads();
        gl_lds16(kgb + (size_t)(j0 + rowi0) * HD + ch0 * 8, ldsK0);
        gl_lds16(kgb + (size_t)(j0 + rowi1) * HD + ch1 * 8, ldsK1);
        gl_lds16(vbase + (size_t)rowi0 * MM + j0 + ch0 * 8, ldsV0);
        gl_lds16(vbase + (size_t)rowi1 * MM + j0 + ch1 * 8, ldsV1);
        __syncthreads();

        // ---- S = Q.K^T for both q-groups (shared K frag reads) ----
        __builtin_amdgcn_s_setprio(1);
        floatx4 s[2][4];
        #pragma unroll
        for (int ks = 0; ks < 4; ks++) {
            const int krow = ks * 16 + cl;
            short8 kf0 = *(const short8*)&L[krow * 64 + fsA * 8];
            short8 kf1 = *(const short8*)&L[krow * 64 + fsB * 8];
            #pragma unroll
            for (int g = 0; g < 2; g++) {
                floatx4 z = (floatx4){0.f, 0.f, 0.f, 0.f};
                z = __builtin_amdgcn_mfma_f32_16x16x32_bf16(qa[g][0], kf0, z, 0, 0, 0);
                z = __builtin_amdgcn_mfma_f32_16x16x32_bf16(qa[g][1], kf1, z, 0, 0, 0);
                s[g][ks] = z;
            }
        }
        __builtin_amdgcn_s_setprio(0);

        // ---- no-max softmax: p = exp(s/8); per-lane partial sums ----
        const bool tailzone = (t >= ntiles - 2);
        #pragma unroll
        for (int g = 0; g < 2; g++) {
            const int qgb = LL + SS + q0 + w * 32 + g * 16;
            #pragma unroll
            for (int ks = 0; ks < 4; ks++) {
                #pragma unroll
                for (int r = 0; r < 4; r++) {
                    float sv = s[g][ks][r] * 0.125f;
                    if (tailzone && (j0 + ks * 16 + cl > qgb + quad * 4 + r))
                        sv = -INFINITY;
                    const float p = __expf(sv);
                    rs[g][r] += p;
                    const int qrw = quad * 4 + r;
                    const int slot = (ks * 2 + (cl >> 3) + 2 * qrw) & 7;
                    L[PS_OFF + w * PSW + (g * 16 + qrw) * PSP + slot * 8 + (cl & 7)] =
                        (short)f2bf(p);
                }
            }
        }

        // wave-private LDS write->read: drain ds queue, pin ordering
        __builtin_amdgcn_s_waitcnt(0xc07f);   // lgkmcnt(0)
        __builtin_amdgcn_wave_barrier();

        // ---- O += P.V (shared V frag reads) ----
        short8 pf[2][2];
        #pragma unroll
        for (int g = 0; g < 2; g++) {
            pf[g][0] = *(const short8*)&L[PS_OFF + w * PSW + (g * 16 + cl) * PSP + psA * 8];
            pf[g][1] = *(const short8*)&L[PS_OFF + w * PSW + (g * 16 + cl) * PSP + psB * 8];
        }
        __builtin_amdgcn_s_setprio(1);
        #pragma unroll
        for (int nt = 0; nt < 4; nt++) {
            const int drow = nt * 16 + cl;
            short8 vf0 = *(const short8*)&L[VS_OFF + drow * 64 + fsA * 8];
            short8 vf1 = *(const short8*)&L[VS_OFF + drow * 64 + fsB * 8];
            #pragma unroll
            for (int g = 0; g < 2; g++) {
                o[g][nt] = __builtin_amdgcn_mfma_f32_16x16x32_bf16(pf[g][0], vf0, o[g][nt], 0, 0, 0);
                o[g][nt] = __builtin_amdgcn_mfma_f32_16x16x32_bf16(pf[g][1], vf1, o[g][nt], 0, 0, 0);
            }
        }
        __builtin_amdgcn_s_setprio(0);
    }

    // ---- deferred l reduction (only shuffles in the kernel) ----
    #pragma unroll
    for (int g = 0; g < 2; g++)
        #pragma unroll
        for (int r = 0; r < 4; r++) {
            float t2 = rs[g][r];
            t2 += __shfl_xor(t2, 1);
            t2 += __shfl_xor(t2, 2);
            t2 += __shfl_xor(t2, 4);
            t2 += __shfl_xor(t2, 8);
            if (cl == 0)
                Lp[piece * 32768 + bh * 1024 + q0 + w * 32 + g * 16 + quad * 4 + r] = t2;
        }

    // ---- stage raw partial O -> coalesced store (Ys = L[0..8704), explicit) ----
    __syncthreads();   // all waves done reading Ks/Vs/Ps
    #pragma unroll
    for (int g = 0; g < 2; g++)
        #pragma unroll
        for (int r = 0; r < 4; r++) {
            const int ql = w * 32 + g * 16 + quad * 4 + r;
            #pragma unroll
            for (int nt = 0; nt < 4; nt++)
                L[ql * 68 + nt * 16 + cl] = (short)f2bf(o[g][nt][r]);
        }
    __syncthreads();
    short* ob = Op + ((size_t)(piece * 32 + bh) * 1024 + q0) * 64;
    #pragma unroll
    for (int it = 0; it < 4; it++) {
        const int idx = it * 2048 + tid * 8;   // q*64 + d, q<128
        const int q = idx >> 6, d = idx & 63;
        short4v v0 = *(const short4v*)&L[q * 68 + d];
        short4v v1 = *(const short4v*)&L[q * 68 + d + 4];
        short8 vv;
        #pragma unroll
        for (int u = 0; u < 4; u++) { vv[u] = v0[u]; vv[u + 4] = v1[u]; }
        *(short8*)(ob + idx) = vv;
    }
}

// ---------------------------------------------------------------------------
// Kernel: combine 4 split-K pieces (raw O sums + l sums) -> Yatt bf16
// ---------------------------------------------------------------------------
__global__ __launch_bounds__(256)
void attn_combine(const short* __restrict__ Op, const float* __restrict__ Lp,
                  short* __restrict__ Yatt)
{
    const int idx = blockIdx.x * 256 + threadIdx.x;   // < 262144
    const int row = idx >> 3;            // bh*1024 + q
    const int seg = (idx & 7) << 3;
    const float lsum = Lp[row] + Lp[32768 + row] + Lp[65536 + row] + Lp[98304 + row];
    const float inv = 1.0f / lsum;
    float acc[8] = {0.f, 0.f, 0.f, 0.f, 0.f, 0.f, 0.f, 0.f};
    #pragma unroll
    for (int p = 0; p < 4; p++) {
        short8 v = *(const short8*)(Op + ((size_t)(p * 32768) + row) * 64 + seg);
        #pragma unroll
        for (int u = 0; u < 8; u++) acc[u] += bf2f(v[u]);
    }
    short8 o8;
    #pragma unroll
    for (int u = 0; u < 8; u++) o8[u] = (short)f2bf(acc[u] * inv);
    const int bh = row >> 10, q = row & 1023;
    const int b = bh >> 4, h = bh & 15;
    *(short8*)(Yatt + ((size_t)b * TT + q) * CC + h * 64 + seg) = o8;
}

// ---------------------------------------------------------------------------
// Kernel: proj MFMA GEMM, 64x64 tiles (512 blocks -> 2/CU) — r4-proven
// version. 4 waves 2x2, each wave 32x32. Async staging.
// ---------------------------------------------------------------------------
__global__ __launch_bounds__(256)
void proj_gemm(const short* __restrict__ A, const short* __restrict__ Bt,
               float* __restrict__ Co)
{
    __shared__ short As[64 * 32];
    __shared__ short Bs[64 * 32];
    const int row0 = blockIdx.y * 64, col0 = blockIdx.x * 64;
    const int tid = threadIdx.x;
    const int w = tid >> 6, l = tid & 63, quad = l >> 4, cl = l & 15;
    const int wr = w >> 1, wc = w & 1;

    const int srow = tid >> 2;               // 0..63
    const int schunk = ((tid & 3) - ((srow & 15) >> 1)) & 3;
    const short* gA = A + (size_t)(row0 + srow) * CC + schunk * 8;
    const short* gB = Bt + (size_t)(col0 + srow) * CC + schunk * 8;
    short* lA = &As[tid * 8];
    short* lB = &Bs[tid * 8];

    const int fs = (quad + (cl >> 1)) & 3;

    floatx4 acc[2][2];
    #pragma unroll
    for (int mi = 0; mi < 2; mi++)
        #pragma unroll
        for (int ni = 0; ni < 2; ni++) acc[mi][ni] = (floatx4){0.f, 0.f, 0.f, 0.f};

    for (int k0 = 0; k0 < CC; k0 += 32) {
        __syncthreads();
        gl_lds16(gA + k0, lA);
        gl_lds16(gB + k0, lB);
        __syncthreads();
        short8 af[2], bf[2];
        #pragma unroll
        for (int mi = 0; mi < 2; mi++)
            af[mi] = *(const short8*)&As[(wr * 32 + mi * 16 + cl) * 32 + fs * 8];
        #pragma unroll
        for (int ni = 0; ni < 2; ni++)
            bf[ni] = *(const short8*)&Bs[(wc * 32 + ni * 16 + cl) * 32 + fs * 8];
        #pragma unroll
        for (int mi = 0; mi < 2; mi++)
            #pragma unroll
            for (int ni = 0; ni < 2; ni++)
                acc[mi][ni] = __builtin_amdgcn_mfma_f32_16x16x32_bf16(
                    af[mi], bf[ni], acc[mi][ni], 0, 0, 0);
    }
    #pragma unroll
    for (int mi = 0; mi < 2; mi++)
        #pragma unroll
        for (int ni = 0; ni < 2; ni++)
            #pragma unroll
            for (int r = 0; r < 4; r++)
                Co[(size_t)(row0 + wr * 32 + mi * 16 + quad * 4 + r) * CC
                   + col0 + wc * 32 + ni * 16 + cl] = acc[mi][ni][r];
}

// ---------------------------------------------------------------------------
extern "C" void kernel_launch(void* const* d_in, const int* in_sizes, int n_in,
                              void* d_out, int out_size, void* d_ws, size_t ws_size,
                              hipStream_t stream)
{
    (void)in_sizes; (void)n_in; (void)out_size; (void)ws_size;
    const float* x      = (const float*)d_in[0];
    const float* stm    = (const float*)d_in[1];
    // d_in[2] = long_q: unused (output slice only covers query rows >= L+S)
    const float* long_k = (const float*)d_in[3];
    const float* long_v = (const float*)d_in[4];
    const float* w_attn = (const float*)d_in[5];
    const float* w_proj = (const float*)d_in[6];
    float* out = (float*)d_out;

    short* Xb   = (short*)d_ws;                 // 3,145,728
    short* WaT  = Xb   + (size_t)3145728;       // 3,145,728
    short* WpT  = WaT  + (size_t)3145728;       // 1,048,576
    short* Qb   = WpT  + (size_t)1048576;       // 2,097,152
    short* Kb   = Qb   + (size_t)2097152;       // 5,242,880
    short* Vtr  = Kb   + (size_t)5242880;       // 5,242,880
    short* Yb   = Vtr  + (size_t)5242880;       // 2,097,152
    float* RTab = (float*)(Yb + (size_t)2097152);     // 98,304 floats
    short* Opart = (short*)(RTab + 98304);            // 8,388,608 shorts (4 pieces)
    float* Lpart = (float*)(Opart + (size_t)8388608); // 131,072 floats

    prep_all<<<7872, 256, 0, stream>>>(x, stm, w_attn, w_proj, long_k, long_v,
                                       Xb, WaT, WpT, Kb, Vtr, RTab);

    qkv_gemm<<<dim3(48, 12, 2), 256, 0, stream>>>(Xb, WaT, RTab, Qb, Kb, Vtr);

    attn_mfma<<<dim3(32, 8, 4), 256, 0, stream>>>(Qb, Kb, Vtr, Opart, Lpart);
    attn_combine<<<1024, 256, 0, stream>>>(Opart, Lpart, Yb);

    proj_gemm<<<dim3(16, 32), 256, 0, stream>>>(Yb, WpT, out);
}